// Round 6
// baseline (250.493 us; speedup 1.0000x reference)
//
#include <hip/hip_runtime.h>

// SNN forward scan: B=64, N=1024, T=512. Row = (b*N+n), x[row*512 + t].
//
// R13 = R12 with the pipeline ACTUALLY 2 phases deep (placement fix only).
// Convoy model (fits R8/R10/R12): the grid is phase-locked; each phase all
// ~1024 blocks dump a 32-KiB burst at once -> queueing delay ~5-6us == the
// measured 6.6us/phase fixed cost, data-size-independent (R10's flat
// marginal phase cost). R12 issued chunk k+2 at B(k) and waited k+1 in the
// SAME phase B -> only ~1 phase in flight; DMA latency exposed every phase.
// Fix (3 moves, zero structural change):
//   1. issue(k+2) at phase A(k)  [buffer (k+2)%3 is free since END(k-1)]
//   2. wait vmcnt(16) at the END of phase B(k)  [chunk k+1 in-flight
//      window = B(k-1)+A(k)+B(k) ~ 2 full phases]
//   3. tail: k=NCHUNK-2 -> vmcnt(0); k=NCHUNK-1 -> no wait.
// vmcnt(0)-drain never in the main loop (T4). Everything else identical
// to R12: DMA staging, both-sides swizzle, bit-packed spikes, NT stores,
// LDS 50176 B -> 3 blocks/CU.
// Predicted: FETCH ~65.6MB / WRITE ~131MB / conflicts ~0.56M / VGPR ~68
// unchanged; dur 106 -> 55-70us if convoy model right (beats R8's 85.7);
// 85-100 = DMA latency > 2 phases; >=100 falsifies -> pivot to
// barrier-free per-lane-row register kernel.
//
// Numerics: BIT-EXACT vs float32 reference (identical op order; spike
// storage as bits reproduces exact 0.0f/1.0f). contract(off).
#pragma clang fp contract(off)

#define ROWS    64                    // rows per block (1 compute wave)
#define T_LEN   512
#define CHUNK   64                    // timesteps per tile
#define NCHUNK  (T_LEN / CHUNK)       // 8
#define NV      16                    // float4 granules per row per chunk
#define BUFW    (ROWS * CHUNK)        // 4096 floats per inbuf (16 KiB)
#define NPARAM  1024

typedef float f4_nt __attribute__((ext_vector_type(4)));

// lgkmcnt(0)-only barrier: LDS visibility without the vmcnt(0) drain.
#define BARRIER() asm volatile("s_waitcnt lgkmcnt(0)\n\ts_barrier" ::: "memory")

// async global->LDS DMA, 16 B per lane: LDS dest = uniform base + lane*16
#define GLOAD16(gp, lp)                                                \
    __builtin_amdgcn_global_load_lds(                                  \
        (const __attribute__((address_space(1))) void*)(gp),           \
        (__attribute__((address_space(3))) void*)(lp), 16, 0, 0)

__global__ __launch_bounds__(192) void snn_fwd(
    const float* __restrict__ x,
    const float* __restrict__ beta,
    const float* __restrict__ p,
    const float* __restrict__ bparam,
    float* __restrict__ out)
{
    __shared__ __align__(16) float inbuf[3][BUFW];   // 3 x 16384 B, linear
    __shared__ __align__(16) unsigned int outw[ROWS][4];  // 1024 B (bits)

    const int tid     = threadIdx.x;
    const int wid     = tid >> 6;       // 0=compute, 1=load-issue, 2=store
    const int lane    = tid & 63;
    const int rowBase = blockIdx.x * ROWS;

    const float4* __restrict__ xv = (const float4*)x;  // row stride 128 float4
    float4* __restrict__ ov       = (float4*)out;

    // io lane decomposition: lane = r4*16 + t16; instr it covers rows r4+4*it
    const int t16 = lane & 15;
    const int r4  = lane >> 4;
    // load wave: pre-swizzled global granule (even/odd it differ by ^4)
    const int gEven = (rowBase + r4) * (T_LEN / 4) + (t16 ^ r4);
    const int gOdd  = gEven ^ 4;   // (t16^r4)^4 only flips bit2 of granule
    // store wave: identity mapping
    const int gq = (rowBase + r4) * (T_LEN / 4) + t16;

    // compute state
    float mem = 0.0f, refac = 2.0f, a = 0.0f, vth = 1.0f, ps = 0.0f;
    float beta_c = 0.f, p_c = 0.f, b_c = 0.f;
    const int swl   = (lane & 3) | (((lane >> 2) & 1) << 2);  // read swizzle
    const int cbase = lane * NV;                              // float4 units

    if (wid == 0) {
        const int n = (rowBase + lane) & (NPARAM - 1);
        beta_c = fminf(fmaxf(beta[n], 0.001f), 0.999f);
        p_c    = fminf(fabsf(p[n]), 0.999f);
        b_c    = fminf(fmaxf(fabsf(bparam[n]), 0.001f), 1.0f);
    }

    unsigned int b0 = 0, b1 = 0;   // bit-packed spikes for current chunk

    auto step = [&](float xt, unsigned int msk, unsigned int& bw) {
        refac = (ps > 0.0f) ? 0.0f : refac;           // spike-triggered reset
        const float ic = (refac < 2.0f) ? 0.0f : xt;  // refractory input mask
        refac += 1.0f;
        const float nm   = __fadd_rn(__fmul_rn(mem, beta_c), ic);  // integrate
        const float diff = __fsub_rn(nm, vth);
        const bool  sp   = diff > 0.0f;
        const float s    = sp ? 1.0f : 0.0f;
        bw |= sp ? msk : 0u;                          // side-chain, off chain
        mem = sp ? 0.0f : nm;                         // reset-to-zero on spike
        a   = __fadd_rn(__fmul_rn(p_c, a), s);        // adaptation
        vth = __fadd_rn(1.0f, __fmul_rn(b_c, a));     // adaptive threshold
        ps  = s;
    };

    // io wave: issue chunk c's 16 DMA loads into inbuf[buf] (no registers)
    auto issue = [&](int c, int buf) {
        float* lb = &inbuf[buf][0];
        #pragma unroll
        for (int it = 0; it < NV; ++it) {
            const int gidx = ((it & 1) ? gOdd : gEven)
                           + it * 4 * (T_LEN / 4) + c * NV;
            GLOAD16(&xv[gidx], lb + it * 256);   // lane-linear 1 KiB region
        }
    };

    // store wave: expand bits(chunk c) -> float4 NT stores (identity addr)
    auto drain = [&](int c) {
        #pragma unroll
        for (int it = 0; it < NV; ++it) {
            const int row = r4 + 4 * it;
            const uint2 bits = *(const uint2*)&outw[row][0];  // broadcast read
            const unsigned int w = (t16 & 8) ? bits.y : bits.x;
            const int sh = (t16 & 7) * 4;
            float4 sv;
            sv.x = (float)((w >> (sh + 0)) & 1u);
            sv.y = (float)((w >> (sh + 1)) & 1u);
            sv.z = (float)((w >> (sh + 2)) & 1u);
            sv.w = (float)((w >> (sh + 3)) & 1u);
            __builtin_nontemporal_store(
                *reinterpret_cast<f4_nt*>(&sv),
                reinterpret_cast<f4_nt*>(&ov[gq + c * NV + it * 4 * (T_LEN / 4)]));
        }
    };

    // prologue: chunks 0 and 1 in flight; wait chunk 0 only (counted)
    if (wid == 1) {
        issue(0, 0);
        issue(1, 1);
        asm volatile("s_waitcnt vmcnt(16)" ::: "memory");  // 0 landed, 1 flying
    }
    BARRIER();

    int km3 = 0;   // k % 3
    #pragma unroll 1
    for (int k = 0; k < NCHUNK; ++k) {
        // ---- phase A ----
        if (wid == 0) {
            b0 = 0; b1 = 0;
            const float4* ib = (const float4*)inbuf[km3];
            #pragma unroll
            for (int g = 0; g < NV; ++g) {
                const float4 v = ib[cbase + (g ^ swl)];  // ds_read_b128
                const int t = 4 * g;
                if (t < 32) {
                    step(v.x, 1u << (t + 0), b0);
                    step(v.y, 1u << (t + 1), b0);
                    step(v.z, 1u << (t + 2), b0);
                    step(v.w, 1u << (t + 3), b0);
                } else {
                    step(v.x, 1u << (t - 32), b1);
                    step(v.y, 1u << (t - 31), b1);
                    step(v.z, 1u << (t - 30), b1);
                    step(v.w, 1u << (t - 29), b1);
                }
            }
        } else if (wid == 1) {
            // issue 2 chunks ahead into the buffer freed at END(k-1);
            // runs concurrently with compute's phase A.
            if (k + 2 < NCHUNK) {
                int nb = km3 + 2; if (nb >= 3) nb -= 3;
                issue(k + 2, nb);
            }
        } else {
            if (k > 0) drain(k - 1);          // bits published in k-1's B
        }
        BARRIER();  // store's outw reads done before compute rewrites bits
        // ---- phase B ----
        if (wid == 0) {
            *(uint2*)&outw[lane][0] = make_uint2(b0, b1);
        } else if (wid == 1) {
            // wait chunk k+1 (needed at A(k+1)) as LATE as possible:
            // in-flight window ~ 2 full phases. Chunk k+2 stays flying.
            if (k < NCHUNK - 2)
                asm volatile("s_waitcnt vmcnt(16)" ::: "memory");
            else if (k == NCHUNK - 2)
                asm volatile("s_waitcnt vmcnt(0)" ::: "memory");
            // k == NCHUNK-1: nothing outstanding to wait for
        }
        BARRIER();  // bits(k) visible to store; inbuf[(k+1)%3] landed
        ++km3; if (km3 == 3) km3 = 0;
    }
    if (wid == 2) drain(NCHUNK - 1);
}

extern "C" void kernel_launch(void* const* d_in, const int* in_sizes, int n_in,
                              void* d_out, int out_size, void* d_ws, size_t ws_size,
                              hipStream_t stream) {
    const float* x    = (const float*)d_in[0];
    const float* beta = (const float*)d_in[1];
    const float* p    = (const float*)d_in[2];
    const float* b    = (const float*)d_in[3];
    float* out        = (float*)d_out;

    const int BN = 64 * 1024;  // rows
    snn_fwd<<<dim3(BN / ROWS), dim3(192), 0, stream>>>(x, beta, p, b, out);
}

// Round 7
// 244.914 us; speedup vs baseline: 1.0228x; 1.0228x over previous
//
#include <hip/hip_runtime.h>

// SNN forward scan: B=64, N=1024, T=512. Row = (b*N+n), x[row*512 + t].
//
// R14: WRITE RESTRUCTURE. Model (fits R8-R13): phase time ~= loaded load
// latency = in-flight / service-rate (Little); depth changes in-flight AND
// latency together -> no gain (R12->R13). The gate is the 2.2 TB/s service
// rate: all blocks are phase-locked, so the DRAM queue holds reads(chunk k)
// + writes(chunk k-1), both confined to channel residues == c (mod 8)
// (channel = (8r+c) mod NCH; 8r == 0 mod 8 for ANY row mapping -> only c
// moves the low channel bits). The writes are the one stream we can
// re-pattern freely: spikes are 1 bit -> accumulate ALL spikes bit-packed
// in LDS (64 rows x 512 t = 4 KiB/block), then after the loop write the
// block's 128-KiB output region as ONE contiguous sequential burst (all
// channel residues, ideal locality). In-loop HBM = read-only (half LLC-
// resident). Outbuf, store wave, mid barrier all deleted: 2 waves, ONE
// barrier/phase. Everything else = R13 (DMA staging, both-sides swizzle,
// 3 bufs, depth-2 counted vmcnt) -> single-variable experiment.
// LDS 3x16384 + 4096 = 53248 B -> 3 blocks/CU unchanged.
// Predicted: FETCH ~65.6MB, WRITE ~131MB, conflicts ~0.56M, VGPR 48-64;
// dur 92 -> 55-70us if mixed-stream theory right; 85-95 exonerates writes
// -> read pattern is the cap (then: row-skew on read-only loop, or stop).
//
// Numerics: BIT-EXACT vs float32 reference (identical op order; bit
// storage reproduces exact 0.0f/1.0f). contract(off).
#pragma clang fp contract(off)

#define ROWS    64                    // rows per block (1 compute wave)
#define T_LEN   512
#define CHUNK   64                    // timesteps per tile
#define NCHUNK  (T_LEN / CHUNK)       // 8
#define NV      16                    // float4 granules per row per chunk
#define BUFW    (ROWS * CHUNK)        // 4096 floats per inbuf (16 KiB)
#define NPARAM  1024

typedef float f4_nt __attribute__((ext_vector_type(4)));

// lgkmcnt(0)-only barrier: LDS visibility without the vmcnt(0) drain.
#define BARRIER() asm volatile("s_waitcnt lgkmcnt(0)\n\ts_barrier" ::: "memory")

// async global->LDS DMA, 16 B per lane: LDS dest = uniform base + lane*16
#define GLOAD16(gp, lp)                                                \
    __builtin_amdgcn_global_load_lds(                                  \
        (const __attribute__((address_space(1))) void*)(gp),           \
        (__attribute__((address_space(3))) void*)(lp), 16, 0, 0)

__global__ __launch_bounds__(128) void snn_fwd(
    const float* __restrict__ x,
    const float* __restrict__ beta,
    const float* __restrict__ p,
    const float* __restrict__ bparam,
    float* __restrict__ out)
{
    __shared__ __align__(16) float inbuf[3][BUFW];          // 49152 B, linear
    __shared__ __align__(16) unsigned int bitlds[ROWS][16]; //  4096 B (bits)

    const int tid     = threadIdx.x;
    const int wid     = tid >> 6;       // 0=compute, 1=io (DMA issue)
    const int lane    = tid & 63;
    const int rowBase = blockIdx.x * ROWS;

    const float4* __restrict__ xv = (const float4*)x;  // row stride 128 float4
    float4* __restrict__ ov       = (float4*)out;

    // io lane decomposition: lane = r4*16 + t16; instr it covers rows r4+4*it
    const int t16 = lane & 15;
    const int r4  = lane >> 4;
    // pre-swizzled global granule (even/odd it differ by ^4) — G21 pairing
    const int gEven = (rowBase + r4) * (T_LEN / 4) + (t16 ^ r4);
    const int gOdd  = gEven ^ 4;

    // compute state
    float mem = 0.0f, refac = 2.0f, a = 0.0f, vth = 1.0f, ps = 0.0f;
    float beta_c = 0.f, p_c = 0.f, b_c = 0.f;
    const int swl   = (lane & 3) | (((lane >> 2) & 1) << 2);  // read swizzle
    const int cbase = lane * NV;                              // float4 units

    if (wid == 0) {
        const int n = (rowBase + lane) & (NPARAM - 1);
        beta_c = fminf(fmaxf(beta[n], 0.001f), 0.999f);
        p_c    = fminf(fabsf(p[n]), 0.999f);
        b_c    = fminf(fmaxf(fabsf(bparam[n]), 0.001f), 1.0f);
    }

    unsigned int b0 = 0, b1 = 0;   // bit-packed spikes for current chunk

    auto step = [&](float xt, unsigned int msk, unsigned int& bw) {
        refac = (ps > 0.0f) ? 0.0f : refac;           // spike-triggered reset
        const float ic = (refac < 2.0f) ? 0.0f : xt;  // refractory input mask
        refac += 1.0f;
        const float nm   = __fadd_rn(__fmul_rn(mem, beta_c), ic);  // integrate
        const float diff = __fsub_rn(nm, vth);
        const bool  sp   = diff > 0.0f;
        const float s    = sp ? 1.0f : 0.0f;
        bw |= sp ? msk : 0u;                          // side-chain, off chain
        mem = sp ? 0.0f : nm;                         // reset-to-zero on spike
        a   = __fadd_rn(__fmul_rn(p_c, a), s);        // adaptation
        vth = __fadd_rn(1.0f, __fmul_rn(b_c, a));     // adaptive threshold
        ps  = s;
    };

    // io wave: issue chunk c's 16 DMA loads into inbuf[buf] (no registers)
    auto issue = [&](int c, int buf) {
        float* lb = &inbuf[buf][0];
        #pragma unroll
        for (int it = 0; it < NV; ++it) {
            const int gidx = ((it & 1) ? gOdd : gEven)
                           + it * 4 * (T_LEN / 4) + c * NV;
            GLOAD16(&xv[gidx], lb + it * 256);   // lane-linear 1 KiB region
        }
    };

    // prologue: chunks 0 and 1 in flight; wait chunk 0 only (counted)
    if (wid == 1) {
        issue(0, 0);
        issue(1, 1);
        asm volatile("s_waitcnt vmcnt(16)" ::: "memory");  // 0 landed, 1 flying
    }
    BARRIER();

    int km3 = 0;   // k % 3
    #pragma unroll 1
    for (int k = 0; k < NCHUNK; ++k) {
        if (wid == 0) {
            b0 = 0; b1 = 0;
            const float4* ib = (const float4*)inbuf[km3];
            #pragma unroll
            for (int g = 0; g < NV; ++g) {
                const float4 v = ib[cbase + (g ^ swl)];  // ds_read_b128
                const int t = 4 * g;
                if (t < 32) {
                    step(v.x, 1u << (t + 0), b0);
                    step(v.y, 1u << (t + 1), b0);
                    step(v.z, 1u << (t + 2), b0);
                    step(v.w, 1u << (t + 3), b0);
                } else {
                    step(v.x, 1u << (t - 32), b1);
                    step(v.y, 1u << (t - 31), b1);
                    step(v.z, 1u << (t - 30), b1);
                    step(v.w, 1u << (t - 29), b1);
                }
            }
            // publish this chunk's 64 spike bits (one ds_write_b64)
            *(uint2*)&bitlds[lane][2 * k] = make_uint2(b0, b1);
        } else {
            // issue 2 ahead into the buffer freed at the previous barrier;
            // wait chunk k+1 as LATE as possible (in-flight ~2 phases).
            if (k + 2 < NCHUNK) {
                int nb = km3 + 2; if (nb >= 3) nb -= 3;
                issue(k + 2, nb);
            }
            if (k < NCHUNK - 2)
                asm volatile("s_waitcnt vmcnt(16)" ::: "memory");
            else if (k == NCHUNK - 2)
                asm volatile("s_waitcnt vmcnt(0)" ::: "memory");
            // k == NCHUNK-1: nothing outstanding
        }
        BARRIER();  // inbuf[(k+1)%3] landed; bitlds(k) ordered for writeout
        ++km3; if (km3 == 3) km3 = 0;
    }

    // ---- contiguous writeout: 64 rows x 2 KiB = one linear 128-KiB span ----
    // iteration i writes row i: 128 lanes cover float4 q = 0..127 of the row.
    // bits: word = bitlds[i][q>>3], shift base = (q&7)*4  (t = q*4 + e).
    const int obase = rowBase * (T_LEN / 4);   // block's out region, float4
    #pragma unroll 4
    for (int i = 0; i < ROWS; ++i) {
        const unsigned int w = bitlds[i][tid >> 3];   // 8-lane broadcast read
        const int s = (tid & 7) * 4;
        float4 sv;
        sv.x = (float)((w >> (s + 0)) & 1u);
        sv.y = (float)((w >> (s + 1)) & 1u);
        sv.z = (float)((w >> (s + 2)) & 1u);
        sv.w = (float)((w >> (s + 3)) & 1u);
        __builtin_nontemporal_store(
            *reinterpret_cast<f4_nt*>(&sv),
            reinterpret_cast<f4_nt*>(&ov[obase + i * 128 + tid]));
    }
}

extern "C" void kernel_launch(void* const* d_in, const int* in_sizes, int n_in,
                              void* d_out, int out_size, void* d_ws, size_t ws_size,
                              hipStream_t stream) {
    const float* x    = (const float*)d_in[0];
    const float* beta = (const float*)d_in[1];
    const float* p    = (const float*)d_in[2];
    const float* b    = (const float*)d_in[3];
    float* out        = (float*)d_out;

    const int BN = 64 * 1024;  // rows
    snn_fwd<<<dim3(BN / ROWS), dim3(128), 0, stream>>>(x, beta, p, b, out);
}